// Round 1
// baseline (82.987 us; speedup 1.0000x reference)
//
#include <hip/hip_runtime.h>
#include <math.h>

// ChamferLikeDistanceLoss on MI355X (gfx950)
// B=4, 1x64x64 images. out = mean_i min_j |g_i - b_j| + mean_j min_i |g_i - b_j|
// where g = sobel-magnitude(depth_pred), b = boundary_gt, per batch.
//
// Key insight: values are scalars, so min over the pairwise |.| matrix is a
// 1-D nearest-value scan. Brute force = 134M abs/min ops -> VALU-bound, ~µs.
// Single fused kernel: each block re-derives its reference set (Sobel is
// cheap) so there is no inter-kernel dependency.

#define N_PIX 4096   // 64*64
#define BLK   256
#define CHUNKS_PER_IMG 16   // 4096 / 256 points per block

__device__ __forceinline__ float sobel_g(const float* __restrict__ d, int pix) {
    const int y = pix >> 6;
    const int x = pix & 63;
    // zero-padded 3x3 cross-correlation neighborhood
    const float a00 = (y > 0 && x > 0)  ? d[(y - 1) * 64 + (x - 1)] : 0.f;
    const float a01 = (y > 0)           ? d[(y - 1) * 64 + x]       : 0.f;
    const float a02 = (y > 0 && x < 63) ? d[(y - 1) * 64 + (x + 1)] : 0.f;
    const float a10 = (x > 0)           ? d[y * 64 + (x - 1)]       : 0.f;
    const float a12 = (x < 63)          ? d[y * 64 + (x + 1)]       : 0.f;
    const float a20 = (y < 63 && x > 0) ? d[(y + 1) * 64 + (x - 1)] : 0.f;
    const float a21 = (y < 63)          ? d[(y + 1) * 64 + x]       : 0.f;
    const float a22 = (y < 63 && x < 63)? d[(y + 1) * 64 + (x + 1)] : 0.f;
    const float gx = (a00 - a02) + 2.f * (a10 - a12) + (a20 - a22);
    const float gy = (a00 + 2.f * a01 + a02) - (a20 + 2.f * a21 + a22);
    return sqrtf(gx * gx + gy * gy + 1e-8f);
}

__global__ __launch_bounds__(BLK) void chamfer_kernel(
    const float* __restrict__ depth, const float* __restrict__ bnd,
    float* __restrict__ out, int blocks_per_dir, int inv_count_bits /*unused pad*/,
    float inv_count)
{
    __shared__ float refs[N_PIX];
    __shared__ float bsum;

    const int tid = threadIdx.x;
    const int bx  = blockIdx.x;
    const int dir = (bx >= blocks_per_dir) ? 1 : 0;
    const int rem = dir ? (bx - blocks_per_dir) : bx;
    const int batch = rem >> 4;           // CHUNKS_PER_IMG == 16
    const int chunk = rem & (CHUNKS_PER_IMG - 1);

    const float* __restrict__ db = depth + batch * N_PIX;
    const float* __restrict__ bb = bnd   + batch * N_PIX;

    if (tid == 0) bsum = 0.f;

    // Stage the reference set (4096 floats, 16 KiB) into LDS.
    if (dir == 0) {
        // refs = boundary_gt values (dist1: for each g_i, min over b_j)
        const float4* __restrict__ b4 = (const float4*)bb;
        float4* r4 = (float4*)refs;
        #pragma unroll
        for (int j = 0; j < (N_PIX / 4) / BLK; ++j)
            r4[tid + j * BLK] = b4[tid + j * BLK];
    } else {
        // refs = sobel magnitudes (dist2: for each b_j, min over g_i)
        #pragma unroll
        for (int j = 0; j < N_PIX / BLK; ++j) {
            const int p = tid + j * BLK;
            refs[p] = sobel_g(db, p);
        }
    }
    __syncthreads();

    // Query point for this thread.
    const int pix = chunk * BLK + tid;
    const float p = (dir == 0) ? sobel_g(db, pix) : bb[pix];

    // Scan all refs; 4 independent min chains for ILP (only ~2 waves/CU).
    float m0 = 1e30f, m1 = 1e30f, m2 = 1e30f, m3 = 1e30f;
    const float4* __restrict__ r4 = (const float4*)refs;
    #pragma unroll 8
    for (int j = 0; j < N_PIX / 4; ++j) {
        const float4 r = r4[j];
        m0 = fminf(m0, fabsf(p - r.x));
        m1 = fminf(m1, fabsf(p - r.y));
        m2 = fminf(m2, fabsf(p - r.z));
        m3 = fminf(m3, fabsf(p - r.w));
    }
    float m = fminf(fminf(m0, m1), fminf(m2, m3));

    // Wave(64) shuffle reduction -> per-block LDS atomic -> one global atomic.
    #pragma unroll
    for (int o = 32; o > 0; o >>= 1) m += __shfl_down(m, o);
    if ((tid & 63) == 0) atomicAdd(&bsum, m);
    __syncthreads();
    if (tid == 0) atomicAdd(out, bsum * inv_count);
}

extern "C" void kernel_launch(void* const* d_in, const int* in_sizes, int n_in,
                              void* d_out, int out_size, void* d_ws, size_t ws_size,
                              hipStream_t stream) {
    const float* depth = (const float*)d_in[0];
    const float* bnd   = (const float*)d_in[1];
    float* out = (float*)d_out;

    const int B = in_sizes[0] / N_PIX;              // 4
    const int blocks_per_dir = B * CHUNKS_PER_IMG;  // 64
    const int grid = 2 * blocks_per_dir;            // 128
    const float inv_count = 1.0f / (float)(B * N_PIX);  // mean over (B,N)

    // d_out is poisoned 0xAA before every timed launch; zero it (memset node
    // is graph-capturable).
    hipMemsetAsync(out, 0, sizeof(float), stream);
    hipLaunchKernelGGL(chamfer_kernel, dim3(grid), dim3(BLK), 0, stream,
                       depth, bnd, out, blocks_per_dir, 0, inv_count);
}